// Round 11
// baseline (232.631 us; speedup 1.0000x reference)
//
#include <hip/hip_runtime.h>
#include <hip/hip_bf16.h>
#include <stdint.h>

#define NB 32
#define NC 512
#define NP 576
#define NN 4096
#define APANEL8 294912u  // NP*NC bytes (fp8)
#define ATILE8 18432u    // NP*32 bytes per k-tile
#define XPB 2097152u     // per-batch Xp bytes (512*4096 fp8)
#define LOG2E 1.44269504088896340736f

typedef __attribute__((ext_vector_type(4))) float floatx4;

// ---------------- K1: inverse L2 norms over channel dim (patch only) ----------------
__global__ void norms_kernel(const float* __restrict__ in, float* __restrict__ invn,
                             int nsp, int total) {
  int idx = blockIdx.x * 256 + threadIdx.x;
  if (idx >= total) return;
  int b = idx / nsp, sp = idx - b * nsp;
  const float* p = in + (size_t)b * NC * nsp + sp;
  float s = 0.f;
#pragma unroll 8
  for (int c = 0; c < NC; ++c) { float v = p[(size_t)c * nsp]; s = fmaf(v, v, s); }
  invn[idx] = 1.0f / fmaxf(sqrtf(s), 1e-12f);
}

// ---------------- K2: patch [C][P] -> fp8 fragment-tiled A2, scale ----------------
// A2 byte = b*APANEL8 + kt*ATILE8 + (p>>4)*512 + g*128 + (p&15)*8 + e,
// holding c = kt*32 + g*8 + e for row p.
__global__ void transpose_kernel(const float* __restrict__ in, const float* __restrict__ invn,
                                 uint8_t* __restrict__ out, int nsp) {
  __shared__ float tile[64][65];
  int b = blockIdx.z, c0 = blockIdx.y * 64, p0 = blockIdx.x * 64;
  int tx = threadIdx.x & 63, ty = threadIdx.x >> 6;
  const float* src = in + ((size_t)b * NC + c0) * nsp + p0;
#pragma unroll
  for (int r = ty; r < 64; r += 4) tile[r][tx] = src[(size_t)r * nsp + tx];
  __syncthreads();
  int p = p0 + tx;
  float iv = invn[b * nsp + p];
  char* dst = (char*)out + (size_t)b * APANEL8
            + (uint32_t)(p >> 4) * 512u + (uint32_t)(p & 15) * 8u;
#pragma unroll
  for (int q = ty; q < 8; q += 4) {
    int c_local = q * 8, c_global = c0 + c_local;
    float f[8];
#pragma unroll
    for (int e = 0; e < 8; ++e) f[e] = tile[c_local + e][tx] * iv;
    int lo = 0, hi = 0;
    lo = __builtin_amdgcn_cvt_pk_fp8_f32(f[0], f[1], lo, false);
    lo = __builtin_amdgcn_cvt_pk_fp8_f32(f[2], f[3], lo, true);
    hi = __builtin_amdgcn_cvt_pk_fp8_f32(f[4], f[5], hi, false);
    hi = __builtin_amdgcn_cvt_pk_fp8_f32(f[6], f[7], hi, true);
    union { int i2[2]; long l; } u; u.i2[0] = lo; u.i2[1] = hi;
    uint32_t kt = (uint32_t)c_global >> 5, gg = ((uint32_t)c_global >> 3) & 3u;
    *(long*)(dst + kt * ATILE8 + gg * 128u) = u.l;
  }
}

// ---------------- K2b: pack x fp32 -> Xp fp8 in GEMM-fragment layout + sumsq ----
// Xp byte = b*XPB + (j>>6)*32768 + kt*2048 + g*512 + (j&63)*8 + e,
// holding c = kt*32 + g*8 + e for column j. part[b][kt][j] = sumsq over 32 c.
__global__ __launch_bounds__(256) void pack_kernel(const float* __restrict__ x,
                                                   uint8_t* __restrict__ Xp,
                                                   float* __restrict__ part) {
  const int bid = blockIdx.x;                 // 2048 = 32 b * 16 kt * 4 jq
  const int b = bid >> 6, kt = (bid >> 2) & 15, jq = bid & 3;
  const int tid = threadIdx.x;
  const float* xb = x + ((size_t)(b * NC + kt * 32) * NN);
  char* xpb = (char*)Xp + (size_t)b * XPB + (uint32_t)kt * 2048u;
#pragma unroll 1
  for (int i = 0; i < 4; ++i) {
    int j = (jq * 4 + i) * 256 + tid;
    float v[4][8];
#pragma unroll
    for (int g = 0; g < 4; ++g)
#pragma unroll
      for (int e = 0; e < 8; ++e)
        v[g][e] = xb[(size_t)(g * 8 + e) * NN + j];
    float sq = 0.f;
#pragma unroll
    for (int g = 0; g < 4; ++g) {
#pragma unroll
      for (int e = 0; e < 8; ++e) sq = fmaf(v[g][e], v[g][e], sq);
      int lo = 0, hi = 0;
      lo = __builtin_amdgcn_cvt_pk_fp8_f32(v[g][0], v[g][1], lo, false);
      lo = __builtin_amdgcn_cvt_pk_fp8_f32(v[g][2], v[g][3], lo, true);
      hi = __builtin_amdgcn_cvt_pk_fp8_f32(v[g][4], v[g][5], hi, false);
      hi = __builtin_amdgcn_cvt_pk_fp8_f32(v[g][6], v[g][7], hi, true);
      union { int i2[2]; long l; } u; u.i2[0] = lo; u.i2[1] = hi;
      *(long*)(xpb + (uint32_t)(j >> 6) * 32768u + (uint32_t)g * 512u
               + (uint32_t)(j & 63) * 8u) = u.l;
    }
    part[((b * 16 + kt) * 4096) + j] = sq;
  }
}

// ---------------- K2c: invd[b][j] = rsqrt(sum_kt part) * log2e ----------------
__global__ void invd_kernel(const float* __restrict__ part, float* __restrict__ invd) {
  int t = blockIdx.x * 256 + threadIdx.x;     // 32*4096
  int b = t >> 12, j = t & 4095;
  float s = 0.f;
#pragma unroll
  for (int kt = 0; kt < 16; ++kt) s += part[(b * 16 + kt) * 4096 + j];
  invd[t] = rsqrtf(fmaxf(s, 1e-24f)) * LOG2E;
}

// ---------------- K3: fused GEMM + softmax-reduction (plain C, no asm) ----------------
// 2 independent waves per block, no LDS, no barriers. Wave w of block (b,jc)
// computes rows w*288..w*288+287 x cols jc*64..jc*64+63.
// 6 chunks x acc[3][4] (48 AGPR); compiler-managed loads/waits (spill-proof).
__global__ __launch_bounds__(128, 2)
void affinity_kernel(const uint8_t* __restrict__ A2,
                     const uint8_t* __restrict__ Xp,
                     const float* __restrict__ invd,
                     float* __restrict__ partials) {
  const int bid = blockIdx.x;
  const int T = (bid & 7) * 256 + (bid >> 3);   // bijective XCD swizzle (2048 = 8*256)
  const int b = T >> 6, jc = T & 63;
  const int tid = threadIdx.x, lane = tid & 63, w = tid >> 6;
  const int g = lane >> 4, l15 = lane & 15;

  const char* Ab = (const char*)A2 + (size_t)b * APANEL8 + (uint32_t)lane * 8u;
  const char* Xb = (const char*)Xp + (size_t)b * XPB + (uint32_t)jc * 32768u
                 + (uint32_t)g * 512u + (uint32_t)l15 * 8u;

  float iv[4], cxj[4];
#pragma unroll
  for (int q = 0; q < 4; ++q) {
    iv[q] = invd[b * 4096 + jc * 64 + q * 16 + l15];
    cxj[q] = (float)(q * 16 + l15) + 0.5f;   // cx = (j & 63) + 0.5
  }

#pragma unroll 1
  for (int c = 0; c < 6; ++c) {
    floatx4 acc[3][4];
#pragma unroll
    for (int mi = 0; mi < 3; ++mi)
#pragma unroll
      for (int q = 0; q < 4; ++q) acc[mi][q] = (floatx4){0.f, 0.f, 0.f, 0.f};

    const int rg0 = w * 18 + c * 3;           // rowgroup base for this chunk
#pragma unroll
    for (int kt = 0; kt < 16; ++kt) {
      long a[3], bb[4];
#pragma unroll
      for (int mi = 0; mi < 3; ++mi)
        a[mi] = *(const long*)(Ab + (uint32_t)kt * ATILE8 + (uint32_t)(rg0 + mi) * 512u);
#pragma unroll
      for (int q = 0; q < 4; ++q)
        bb[q] = *(const long*)(Xb + (uint32_t)kt * 2048u + (uint32_t)q * 128u);
#pragma unroll
      for (int q = 0; q < 4; ++q)
#pragma unroll
        for (int mi = 0; mi < 3; ++mi)
          acc[mi][q] = __builtin_amdgcn_mfma_f32_16x16x32_fp8_fp8(a[mi], bb[q], acc[mi][q], 0, 0, 0);
    }

    // ---- epilogue for chunk c (cy = jc + 0.5 handled in finalize) ----
#pragma unroll
    for (int mi = 0; mi < 3; ++mi) {
      float s4[4] = {0.f, 0.f, 0.f, 0.f}, sx4[4] = {0.f, 0.f, 0.f, 0.f};
#pragma unroll
      for (int q = 0; q < 4; ++q)
#pragma unroll
        for (int r = 0; r < 4; ++r) {
          float p = exp2f(acc[mi][q][r] * iv[q]);
          s4[r] += p;
          sx4[r] = fmaf(p, cxj[q], sx4[r]);
        }
#pragma unroll
      for (int r = 0; r < 4; ++r) {
#pragma unroll
        for (int m = 1; m < 16; m <<= 1) {
          s4[r] += __shfl_xor(s4[r], m);
          sx4[r] += __shfl_xor(sx4[r], m);
        }
      }
      if (l15 == 0) {
#pragma unroll
        for (int r = 0; r < 4; ++r) {
          int row = (rg0 + mi) * 16 + g * 4 + r;
          float2 o2 = make_float2(s4[r], sx4[r]);
          *(float2*)(partials + ((size_t)(b * NP + row) * 64 + jc) * 2) = o2;
        }
      }
    }
  }
}

// ---------------- K4: finalize ----------------
__global__ void finalize_kernel(const float* __restrict__ partials, float* __restrict__ out) {
  int b = blockIdx.x;
  int t = threadIdx.x;
  float sxt = 0.f, syt = 0.f;
  for (int i = t; i < NP; i += 256) {
    const float* p = partials + ((size_t)(b * NP + i) * 64) * 2;
    float s = 0.f, sx = 0.f, sy = 0.f;
#pragma unroll
    for (int jc2 = 0; jc2 < 64; ++jc2) {
      float ss = p[jc2 * 2];
      s += ss;
      sx += p[jc2 * 2 + 1];
      sy = fmaf(ss, (float)jc2 + 0.5f, sy);
    }
    sxt += sx / s;
    syt += sy / s;
  }
  __shared__ float rs[256], rs2[256];
  rs[t] = sxt; rs2[t] = syt;
  __syncthreads();
  for (int o = 128; o > 0; o >>= 1) {
    if (t < o) { rs[t] += rs[t + o]; rs2[t] += rs2[t + o]; }
    __syncthreads();
  }
  if (t == 0) {
    float cx = rs[0] / (float)NP, cy = rs2[0] / (float)NP;
    float l = fmaxf(cx - 12.f, 0.f);
    float tp = fmaxf(cy - 12.f, 0.f);
    out[b * 4 + 0] = l;
    out[b * 4 + 1] = tp;
    out[b * 4 + 2] = fminf(l + 24.f, 64.f);
    out[b * 4 + 3] = fminf(tp + 24.f, 64.f);
  }
}

extern "C" void kernel_launch(void* const* d_in, const int* in_sizes, int n_in,
                              void* d_out, int out_size, void* d_ws, size_t ws_size,
                              hipStream_t stream) {
  const float* patch_x = (const float*)d_in[0];
  const float* x = (const float*)d_in[1];
  float* out = (float*)d_out;
  char* ws = (char*)d_ws;

  float* inv_src = (float*)(ws + 0);                  //     73,728 B
  uint8_t* A2 = (uint8_t*)(ws + 73728);               //  9,437,184 B (fp8)
  uint8_t* Xp = (uint8_t*)(ws + 9510912);             // 67,108,864 B (fp8)
  float* part = (float*)(ws + 76619776);              //  8,388,608 B
  float* invd = (float*)(ws + 85008384);              //    524,288 B
  float* partials = (float*)(ws + 85532672);          //  9,437,184 B  (end ~95 MB)

  norms_kernel<<<dim3((NB * NP + 255) / 256), 256, 0, stream>>>(patch_x, inv_src, NP, NB * NP);
  transpose_kernel<<<dim3(NP / 64, NC / 64, NB), 256, 0, stream>>>(patch_x, inv_src, A2, NP);
  pack_kernel<<<dim3(2048), 256, 0, stream>>>(x, Xp, part);
  invd_kernel<<<dim3(512), 256, 0, stream>>>(part, invd);
  affinity_kernel<<<dim3(NB * 64), 128, 0, stream>>>(A2, Xp, invd, partials);
  finalize_kernel<<<NB, 256, 0, stream>>>(partials, out);
}

// Round 12
// 220.819 us; speedup vs baseline: 1.0535x; 1.0535x over previous
//
#include <hip/hip_runtime.h>
#include <hip/hip_bf16.h>
#include <stdint.h>

#define NB 32
#define NC 512
#define NP 576
#define NN 4096
#define APANEL8 294912u  // NP*NC bytes (fp8)
#define ATILE8 18432u    // NP*32 bytes per k-tile
#define XPB 2097152u     // per-batch Xp bytes (512*4096 fp8)
#define LOG2E 1.44269504088896340736f

typedef __attribute__((ext_vector_type(4))) float floatx4;

#define AS1 __attribute__((address_space(1)))
#define AS3 __attribute__((address_space(3)))

static __device__ __forceinline__ void gl_lds16(const void* g, void* l) {
  __builtin_amdgcn_global_load_lds((const AS1 uint32_t*)g, (AS3 uint32_t*)l, 16, 0, 0);
}

#define GLOAD_B64(dst, voff, sbase) \
  asm volatile("global_load_dwordx2 %0, %1, %2" : "=v"(dst) : "v"(voff), "s"(sbase))
#define WAIT_VMCNT(N) asm volatile("s_waitcnt vmcnt(" #N ")" ::: "memory")
#define SBAR() __builtin_amdgcn_s_barrier()
#define SCHEDBAR() __builtin_amdgcn_sched_barrier(0)

// ---------------- K1: inverse L2 norms over channel dim (patch only) ----------------
__global__ void norms_kernel(const float* __restrict__ in, float* __restrict__ invn,
                             int nsp, int total) {
  int idx = blockIdx.x * 256 + threadIdx.x;
  if (idx >= total) return;
  int b = idx / nsp, sp = idx - b * nsp;
  const float* p = in + (size_t)b * NC * nsp + sp;
  float s = 0.f;
#pragma unroll 8
  for (int c = 0; c < NC; ++c) { float v = p[(size_t)c * nsp]; s = fmaf(v, v, s); }
  invn[idx] = 1.0f / fmaxf(sqrtf(s), 1e-12f);
}

// ---------------- K2: patch [C][P] -> fp8 fragment-tiled A2, scale ----------------
// A2 byte = b*APANEL8 + kt*ATILE8 + rg*512 + g*128 + (p&15)*8 + e  (rg = p>>4),
// holding c = kt*32 + g*8 + e for row p.
__global__ void transpose_kernel(const float* __restrict__ in, const float* __restrict__ invn,
                                 uint8_t* __restrict__ out, int nsp) {
  __shared__ float tile[64][65];
  int b = blockIdx.z, c0 = blockIdx.y * 64, p0 = blockIdx.x * 64;
  int tx = threadIdx.x & 63, ty = threadIdx.x >> 6;
  const float* src = in + ((size_t)b * NC + c0) * nsp + p0;
#pragma unroll
  for (int r = ty; r < 64; r += 4) tile[r][tx] = src[(size_t)r * nsp + tx];
  __syncthreads();
  int p = p0 + tx;
  float iv = invn[b * nsp + p];
  char* dst = (char*)out + (size_t)b * APANEL8
            + (uint32_t)(p >> 4) * 512u + (uint32_t)(p & 15) * 8u;
#pragma unroll
  for (int q = ty; q < 8; q += 4) {
    int c_local = q * 8, c_global = c0 + c_local;
    float f[8];
#pragma unroll
    for (int e = 0; e < 8; ++e) f[e] = tile[c_local + e][tx] * iv;
    int lo = 0, hi = 0;
    lo = __builtin_amdgcn_cvt_pk_fp8_f32(f[0], f[1], lo, false);
    lo = __builtin_amdgcn_cvt_pk_fp8_f32(f[2], f[3], lo, true);
    hi = __builtin_amdgcn_cvt_pk_fp8_f32(f[4], f[5], hi, false);
    hi = __builtin_amdgcn_cvt_pk_fp8_f32(f[6], f[7], hi, true);
    union { int i2[2]; long l; } u; u.i2[0] = lo; u.i2[1] = hi;
    uint32_t kt = (uint32_t)c_global >> 5, gg = ((uint32_t)c_global >> 3) & 3u;
    *(long*)(dst + kt * ATILE8 + gg * 128u) = u.l;
  }
}

// ---------------- K2b: pack x fp32 -> Xp fp8 in GEMM-fragment layout + sumsq ----
// Xp byte = b*XPB + (j>>6)*32768 + kt*2048 + g*512 + (j&63)*8 + e,
// holding c = kt*32 + g*8 + e for column j. part[b][kt][j] = sumsq over 32 c.
__global__ __launch_bounds__(256) void pack_kernel(const float* __restrict__ x,
                                                   uint8_t* __restrict__ Xp,
                                                   float* __restrict__ part) {
  const int bid = blockIdx.x;                 // 2048 = 32 b * 16 kt * 4 jq
  const int b = bid >> 6, kt = (bid >> 2) & 15, jq = bid & 3;
  const int tid = threadIdx.x;
  const float* xb = x + ((size_t)(b * NC + kt * 32) * NN);
  char* xpb = (char*)Xp + (size_t)b * XPB + (uint32_t)kt * 2048u;
#pragma unroll 1
  for (int i = 0; i < 4; ++i) {
    int j = (jq * 4 + i) * 256 + tid;
    float v[4][8];
#pragma unroll
    for (int g = 0; g < 4; ++g)
#pragma unroll
      for (int e = 0; e < 8; ++e)
        v[g][e] = xb[(size_t)(g * 8 + e) * NN + j];
    float sq = 0.f;
#pragma unroll
    for (int g = 0; g < 4; ++g) {
#pragma unroll
      for (int e = 0; e < 8; ++e) sq = fmaf(v[g][e], v[g][e], sq);
      int lo = 0, hi = 0;
      lo = __builtin_amdgcn_cvt_pk_fp8_f32(v[g][0], v[g][1], lo, false);
      lo = __builtin_amdgcn_cvt_pk_fp8_f32(v[g][2], v[g][3], lo, true);
      hi = __builtin_amdgcn_cvt_pk_fp8_f32(v[g][4], v[g][5], hi, false);
      hi = __builtin_amdgcn_cvt_pk_fp8_f32(v[g][6], v[g][7], hi, true);
      union { int i2[2]; long l; } u; u.i2[0] = lo; u.i2[1] = hi;
      *(long*)(xpb + (uint32_t)(j >> 6) * 32768u + (uint32_t)g * 512u
               + (uint32_t)(j & 63) * 8u) = u.l;
    }
    part[((b * 16 + kt) * 4096) + j] = sq;
  }
}

// ---------------- K2c: invd[b][j] = rsqrt(sum_kt part) * log2e ----------------
__global__ void invd_kernel(const float* __restrict__ part, float* __restrict__ invd) {
  int t = blockIdx.x * 256 + threadIdx.x;     // 32*4096
  int b = t >> 12, j = t & 4095;
  float s = 0.f;
#pragma unroll
  for (int kt = 0; kt < 16; ++kt) s += part[(b * 16 + kt) * 4096 + j];
  invd[t] = rsqrtf(fmaxf(s, 1e-24f)) * LOG2E;
}

// ---------------- K3: GEMM + softmax-reduction, B-panel in LDS ----------------
// Block = 4 waves, one (b,jc). Prologue: stage 32KB fragment-tiled B via
// global_load_lds (linear->linear), ONE barrier. Then barrier-free: wave w
// owns rows w*144.., 16 k-steps x (9 A-b64 ping-pong vmcnt(9) + 4 LDS b64 +
// 36 MFMA), acc[9][4], single epilogue after vmcnt(0).
__global__ __launch_bounds__(256, 2)
void affinity_kernel(const uint8_t* __restrict__ A2,
                     const uint8_t* __restrict__ Xp,
                     const float* __restrict__ invd,
                     float* __restrict__ partials) {
  const int bid = blockIdx.x;
  const int T = (bid & 7) * 256 + (bid >> 3);   // bijective XCD swizzle (2048 = 8*256)
  const int b = T >> 6, jc = T & 63;
  const int tid = threadIdx.x, lane = tid & 63, w = tid >> 6;
  const int g = lane >> 4, l15 = lane & 15;

  __shared__ __align__(16) char Bsh[32768];

  const uint64_t sA = (uint64_t)(uintptr_t)A2;

  // iv/cxj first: plain loads, force completion BEFORE any asm VMEM issues
  float iv[4], cxj[4];
#pragma unroll
  for (int q = 0; q < 4; ++q) {
    iv[q] = invd[b * 4096 + jc * 64 + q * 16 + l15];
    cxj[q] = (float)(q * 16 + l15) + 0.5f;   // cx = (j & 63) + 0.5
  }
  asm volatile("" :: "v"(iv[0]), "v"(iv[1]), "v"(iv[2]), "v"(iv[3]));
  SCHEDBAR();

  // ---- stage B panel: 8 x global_load_lds (1 KB each) per wave ----
  const char* xsrc = (const char*)Xp + (size_t)b * XPB + (uint32_t)jc * 32768u
                   + (uint32_t)w * 8192u + (uint32_t)lane * 16u;
#pragma unroll
  for (int i = 0; i < 8; ++i)
    gl_lds16(xsrc + i * 1024, (char*)Bsh + (uint32_t)w * 8192u + (uint32_t)i * 1024u);

  // ---- A-frag voffsets: rowgroup rg = w*9 + mi, byte rg*512 + lane*8 ----
  uint32_t voffA[9];
#pragma unroll
  for (int mi = 0; mi < 9; ++mi)
    voffA[mi] = (uint32_t)b * APANEL8 + (uint32_t)(w * 9 + mi) * 512u
              + (uint32_t)lane * 8u;

  long afA[9], afB[9];
  auto issueA = [&](int t, long (&af)[9]) {
    uint64_t aoff = sA + (uint64_t)((uint32_t)t * ATILE8);
#pragma unroll
    for (int mi = 0; mi < 9; ++mi) GLOAD_B64(af[mi], voffA[mi], aoff);
  };

  issueA(0, afA);                 // queue: stage[8] + A0[9]
  issueA(1, afB);                 // + A1[9] = 26
  WAIT_VMCNT(18); SCHEDBAR();     // stage done (own wave's 8)
  SBAR();                         // all waves staged; LAST barrier

  floatx4 acc[9][4];
#pragma unroll
  for (int mi = 0; mi < 9; ++mi)
#pragma unroll
    for (int q = 0; q < 4; ++q) acc[mi][q] = (floatx4){0.f, 0.f, 0.f, 0.f};

  auto mfmaStep = [&](int kt, long (&af)[9]) {
#pragma unroll
    for (int q = 0; q < 4; ++q) {
      long bf = *(const long*)(Bsh + (uint32_t)kt * 2048u + (uint32_t)g * 512u
                               + (uint32_t)q * 128u + (uint32_t)l15 * 8u);
#pragma unroll
      for (int mi = 0; mi < 9; ++mi)
        acc[mi][q] = __builtin_amdgcn_mfma_f32_16x16x32_fp8_fp8(af[mi], bf, acc[mi][q], 0, 0, 0);
    }
  };

#pragma unroll 2
  for (int kt = 0; kt < 14; ++kt) {
    WAIT_VMCNT(9); SCHEDBAR();    // A(kt) home
    if (kt & 1) { mfmaStep(kt, afB); issueA(kt + 2, afB); }
    else        { mfmaStep(kt, afA); issueA(kt + 2, afA); }
  }
  WAIT_VMCNT(9); SCHEDBAR();      // A14 home; A15 in flight
  mfmaStep(14, afA);
  WAIT_VMCNT(0); SCHEDBAR();      // A15 home
  mfmaStep(15, afB);

  // ---- epilogue (cy = jc + 0.5 handled in finalize) ----
#pragma unroll
  for (int mi = 0; mi < 9; ++mi) {
    float s4[4] = {0.f, 0.f, 0.f, 0.f}, sx4[4] = {0.f, 0.f, 0.f, 0.f};
#pragma unroll
    for (int q = 0; q < 4; ++q)
#pragma unroll
      for (int r = 0; r < 4; ++r) {
        float p = exp2f(acc[mi][q][r] * iv[q]);
        s4[r] += p;
        sx4[r] = fmaf(p, cxj[q], sx4[r]);
      }
#pragma unroll
    for (int r = 0; r < 4; ++r) {
#pragma unroll
      for (int m = 1; m < 16; m <<= 1) {
        s4[r] += __shfl_xor(s4[r], m);
        sx4[r] += __shfl_xor(sx4[r], m);
      }
    }
    if (l15 == 0) {
#pragma unroll
      for (int r = 0; r < 4; ++r) {
        int row = (w * 9 + mi) * 16 + g * 4 + r;
        float2 o2 = make_float2(s4[r], sx4[r]);
        *(float2*)(partials + ((size_t)(b * NP + row) * 64 + jc) * 2) = o2;
      }
    }
  }
}

// ---------------- K4: finalize ----------------
__global__ void finalize_kernel(const float* __restrict__ partials, float* __restrict__ out) {
  int b = blockIdx.x;
  int t = threadIdx.x;
  float sxt = 0.f, syt = 0.f;
  for (int i = t; i < NP; i += 256) {
    const float* p = partials + ((size_t)(b * NP + i) * 64) * 2;
    float s = 0.f, sx = 0.f, sy = 0.f;
#pragma unroll
    for (int jc2 = 0; jc2 < 64; ++jc2) {
      float ss = p[jc2 * 2];
      s += ss;
      sx += p[jc2 * 2 + 1];
      sy = fmaf(ss, (float)jc2 + 0.5f, sy);
    }
    sxt += sx / s;
    syt += sy / s;
  }
  __shared__ float rs[256], rs2[256];
  rs[t] = sxt; rs2[t] = syt;
  __syncthreads();
  for (int o = 128; o > 0; o >>= 1) {
    if (t < o) { rs[t] += rs[t + o]; rs2[t] += rs2[t + o]; }
    __syncthreads();
  }
  if (t == 0) {
    float cx = rs[0] / (float)NP, cy = rs2[0] / (float)NP;
    float l = fmaxf(cx - 12.f, 0.f);
    float tp = fmaxf(cy - 12.f, 0.f);
    out[b * 4 + 0] = l;
    out[b * 4 + 1] = tp;
    out[b * 4 + 2] = fminf(l + 24.f, 64.f);
    out[b * 4 + 3] = fminf(tp + 24.f, 64.f);
  }
}

extern "C" void kernel_launch(void* const* d_in, const int* in_sizes, int n_in,
                              void* d_out, int out_size, void* d_ws, size_t ws_size,
                              hipStream_t stream) {
  const float* patch_x = (const float*)d_in[0];
  const float* x = (const float*)d_in[1];
  float* out = (float*)d_out;
  char* ws = (char*)d_ws;

  float* inv_src = (float*)(ws + 0);                  //     73,728 B
  uint8_t* A2 = (uint8_t*)(ws + 73728);               //  9,437,184 B (fp8)
  uint8_t* Xp = (uint8_t*)(ws + 9510912);             // 67,108,864 B (fp8)
  float* part = (float*)(ws + 76619776);              //  8,388,608 B
  float* invd = (float*)(ws + 85008384);              //    524,288 B
  float* partials = (float*)(ws + 85532672);          //  9,437,184 B  (end ~95 MB)

  norms_kernel<<<dim3((NB * NP + 255) / 256), 256, 0, stream>>>(patch_x, inv_src, NP, NB * NP);
  transpose_kernel<<<dim3(NP / 64, NC / 64, NB), 256, 0, stream>>>(patch_x, inv_src, A2, NP);
  pack_kernel<<<dim3(2048), 256, 0, stream>>>(x, Xp, part);
  invd_kernel<<<dim3(512), 256, 0, stream>>>(part, invd);
  affinity_kernel<<<dim3(NB * 64), 256, 0, stream>>>(A2, Xp, invd, partials);
  finalize_kernel<<<NB, 256, 0, stream>>>(partials, out);
}

// Round 13
// 162.791 us; speedup vs baseline: 1.4290x; 1.3565x over previous
//
#include <hip/hip_runtime.h>
#include <hip/hip_bf16.h>
#include <stdint.h>

#define NB 32
#define NC 512
#define NP 576
#define NN 4096
#define APANEL8 294912u  // NP*NC bytes (fp8)
#define ATILE8 18432u    // NP*32 bytes per k-tile
#define LOG2E 1.44269504088896340736f

typedef __attribute__((ext_vector_type(4))) float floatx4;

#define GLOAD_F32(dst, voff, sbase) \
  asm volatile("global_load_dword %0, %1, %2" : "=v"(dst) : "v"(voff), "s"(sbase))
#define GLOAD_B64(dst, voff, sbase) \
  asm volatile("global_load_dwordx2 %0, %1, %2" : "=v"(dst) : "v"(voff), "s"(sbase))
#define DSWRITE_B64(addr, data) \
  asm volatile("ds_write_b64 %0, %1" :: "v"(addr), "v"(data) : "memory")
#define WAIT_VMCNT(N) asm volatile("s_waitcnt vmcnt(" #N ")" ::: "memory")
#define WAIT_LGKM0    asm volatile("s_waitcnt lgkmcnt(0)" ::: "memory")
#define SBAR() do { asm volatile("" ::: "memory"); __builtin_amdgcn_s_barrier(); asm volatile("" ::: "memory"); } while (0)
#define SCHEDBAR() __builtin_amdgcn_sched_barrier(0)

// ---------------- K1: inverse L2 norms over channel dim (patch only) ----------------
__global__ void norms_kernel(const float* __restrict__ in, float* __restrict__ invn,
                             int nsp, int total) {
  int idx = blockIdx.x * 256 + threadIdx.x;
  if (idx >= total) return;
  int b = idx / nsp, sp = idx - b * nsp;
  const float* p = in + (size_t)b * NC * nsp + sp;
  float s = 0.f;
#pragma unroll 8
  for (int c = 0; c < NC; ++c) { float v = p[(size_t)c * nsp]; s = fmaf(v, v, s); }
  invn[idx] = 1.0f / fmaxf(sqrtf(s), 1e-12f);
}

// ---------------- K2: patch [C][P] -> fp8 fragment-tiled A2, scale ----------------
// A2 byte = b*APANEL8 + kt*ATILE8 + (p>>4)*512 + g*128 + (p&15)*8 + e,
// holding c = kt*32 + g*8 + e for row p.
__global__ void transpose_kernel(const float* __restrict__ in, const float* __restrict__ invn,
                                 uint8_t* __restrict__ out, int nsp) {
  __shared__ float tile[64][65];
  int b = blockIdx.z, c0 = blockIdx.y * 64, p0 = blockIdx.x * 64;
  int tx = threadIdx.x & 63, ty = threadIdx.x >> 6;
  const float* src = in + ((size_t)b * NC + c0) * nsp + p0;
#pragma unroll
  for (int r = ty; r < 64; r += 4) tile[r][tx] = src[(size_t)r * nsp + tx];
  __syncthreads();
  int p = p0 + tx;
  float iv = invn[b * nsp + p];
  char* dst = (char*)out + (size_t)b * APANEL8
            + (uint32_t)(p >> 4) * 512u + (uint32_t)(p & 15) * 8u;
#pragma unroll
  for (int q = ty; q < 8; q += 4) {
    int c_local = q * 8, c_global = c0 + c_local;
    float f[8];
#pragma unroll
    for (int e = 0; e < 8; ++e) f[e] = tile[c_local + e][tx] * iv;
    int lo = 0, hi = 0;
    lo = __builtin_amdgcn_cvt_pk_fp8_f32(f[0], f[1], lo, false);
    lo = __builtin_amdgcn_cvt_pk_fp8_f32(f[2], f[3], lo, true);
    hi = __builtin_amdgcn_cvt_pk_fp8_f32(f[4], f[5], hi, false);
    hi = __builtin_amdgcn_cvt_pk_fp8_f32(f[6], f[7], hi, true);
    union { int i2[2]; long l; } u; u.i2[0] = lo; u.i2[1] = hi;
    uint32_t kt = (uint32_t)c_global >> 5, gg = ((uint32_t)c_global >> 3) & 3u;
    *(long*)(dst + kt * ATILE8 + gg * 128u) = u.l;
  }
}

// ---------------- K3: fused pack + GEMM + softmax-reduction ----------------
// 1024 blocks (32 b x 32 jc of 128 cols), 512 thr / 8 waves, 1 block/CU.
// Per k-step: all threads reg-stage the 16KB fp32 x-tile (depth-2 GA/GB),
// cvt->fp8 -> one ds_write_b64 into 4KB fragment-layout LDS (double-buffered).
// A-frags from fragment-tiled A2 (L2-hot). One combined vmcnt(8) per step.
// x is read EXACTLY ONCE from HBM; sumsq rides the cvt.
__global__ __launch_bounds__(512, 2)
void affinity_kernel(const uint8_t* __restrict__ A2,
                     const float* __restrict__ x,
                     float* __restrict__ partials) {
  const int bid = blockIdx.x;
  const int T = (bid & 7) * 128 + (bid >> 3);   // bijective XCD swizzle (1024 = 8*128)
  const int b = T >> 5, jc = T & 31;
  const int tid = threadIdx.x, lane = tid & 63, w = tid >> 6;
  const int wm = w & 3, wn = w >> 2;
  const int g = lane >> 4, l15 = lane & 15;
  const int sg = tid >> 7, jloc = tid & 127;

  __shared__ __align__(16) char Bsh[8192];   // 2 x [32k x 128j] fp8, fragment layout
  __shared__ float sqx[4][128];
  __shared__ float invd[128];

  const uint64_t sA = (uint64_t)(uintptr_t)A2;
  const uint64_t sX = (uint64_t)(uintptr_t)x;

  // X stage: thread (sg, jloc) loads c = kt*32 + sg*8 + e, col jc*128 + jloc
  const uint32_t voffX0 = (uint32_t)((b * NC + sg * 8) * NN + jc * 128 + jloc) * 4u;
  // A frags: rowgroup rg = wm*9 + mi
  uint32_t voffA[9];
#pragma unroll
  for (int mi = 0; mi < 9; ++mi)
    voffA[mi] = (uint32_t)b * APANEL8 + (uint32_t)(wm * 9 + mi) * 512u
              + (uint32_t)lane * 8u;

  const uint32_t wrbase = (uint32_t)(uintptr_t)(&Bsh[0])
                        + (uint32_t)sg * 1024u + (uint32_t)jloc * 8u;

  floatx4 acc[9][4];
#pragma unroll
  for (int mi = 0; mi < 9; ++mi)
#pragma unroll
    for (int q = 0; q < 4; ++q) acc[mi][q] = (floatx4){0.f, 0.f, 0.f, 0.f};

  float GA[8], GB[8];
  long af[9];
  float sq = 0.f;

  auto issueX = [&](int kt, float (&G)[8]) {
#pragma unroll
    for (int e = 0; e < 8; ++e)
      GLOAD_F32(G[e], voffX0 + (uint32_t)kt * 524288u + (uint32_t)e * 16384u, sX);
  };
  auto issueA = [&](int kt) {
#pragma unroll
    for (int mi = 0; mi < 9; ++mi)
      GLOAD_B64(af[mi], voffA[mi] + (uint32_t)kt * ATILE8, sA);
  };
  auto cvtW = [&](float (&G)[8], uint32_t bufoff) {
#pragma unroll
    for (int e = 0; e < 8; ++e) sq = fmaf(G[e], G[e], sq);
    int lo = 0, hi = 0;
    lo = __builtin_amdgcn_cvt_pk_fp8_f32(G[0], G[1], lo, false);
    lo = __builtin_amdgcn_cvt_pk_fp8_f32(G[2], G[3], lo, true);
    hi = __builtin_amdgcn_cvt_pk_fp8_f32(G[4], G[5], hi, false);
    hi = __builtin_amdgcn_cvt_pk_fp8_f32(G[6], G[7], hi, true);
    union { int i2[2]; long l; } u; u.i2[0] = lo; u.i2[1] = hi;
    DSWRITE_B64(wrbase + bufoff, u.l);
  };
  auto mfmaStep = [&](uint32_t bufoff) {
#pragma unroll
    for (int q = 0; q < 4; ++q) {
      long bf = *(const long*)(Bsh + bufoff + (uint32_t)g * 1024u
                               + (uint32_t)(wn * 64 + q * 16 + l15) * 8u);
#pragma unroll
      for (int mi = 0; mi < 9; ++mi)
        acc[mi][q] = __builtin_amdgcn_mfma_f32_16x16x32_fp8_fp8(af[mi], bf, acc[mi][q], 0, 0, 0);
    }
  };

  // ---- prologue: X0->GA, X1->GB, A0->af; buf0 = X0 ----
  issueX(0, GA);
  issueX(1, GB);
  issueA(0);
  WAIT_VMCNT(17); SCHEDBAR();     // X0 home; queue: X1[8] A0[9] = 17
  cvtW(GA, 0u);
  WAIT_LGKM0;
  SBAR();

  // ---- main loop: steps 0..13 (x2 unroll) ----
#pragma unroll 1
  for (int kt = 0; kt < 14; kt += 2) {
    // even step kt: consume buf0 + A(kt); cvt X(kt+1)(GB) -> buf1
    issueX(kt + 2, GA);           // queue: X(kt+1)8 A(kt)9 X(kt+2)8 = 25
    WAIT_VMCNT(8); SCHEDBAR();    // X(kt+1)+A(kt) home; X(kt+2) in flight
    mfmaStep(0u);
    issueA(kt + 1);               // queue: X(kt+2)8 A(kt+1)9 = 17
    cvtW(GB, 4096u);
    WAIT_LGKM0;
    SBAR();
    // odd step kt+1: consume buf1 + A(kt+1); cvt X(kt+2)(GA) -> buf0
    issueX(kt + 3, GB);
    WAIT_VMCNT(8); SCHEDBAR();
    mfmaStep(4096u);
    issueA(kt + 2);
    cvtW(GA, 0u);
    WAIT_LGKM0;
    SBAR();
  }
  // ---- step 14: queue [X15(8), A14(9)] ----
  WAIT_VMCNT(0); SCHEDBAR();      // X15 + A14 home
  mfmaStep(0u);
  issueA(15);
  cvtW(GB, 4096u);
  WAIT_LGKM0;
  SBAR();
  // ---- step 15 ----
  WAIT_VMCNT(0); SCHEDBAR();      // A15 home
  mfmaStep(4096u);

  // ---- dst inv-norms ----
  sqx[sg][jloc] = sq;
  __syncthreads();
  if (tid < 128)
    invd[tid] = rsqrtf(fmaxf(sqx[0][tid] + sqx[1][tid] + sqx[2][tid] + sqx[3][tid],
                             1e-24f)) * LOG2E;
  __syncthreads();

  // ---- epilogue: exp2 + weighted reduce; cy handled in finalize ----
  const int jcol = jc * 2 + wn;   // 64-col unit index for finalize
#pragma unroll
  for (int mi = 0; mi < 9; ++mi) {
    float s4[4] = {0.f, 0.f, 0.f, 0.f}, sx4[4] = {0.f, 0.f, 0.f, 0.f};
#pragma unroll
    for (int q = 0; q < 4; ++q) {
      float ivq = invd[wn * 64 + q * 16 + l15];
      float cx = (float)(q * 16 + l15) + 0.5f;
#pragma unroll
      for (int r = 0; r < 4; ++r) {
        float p = exp2f(acc[mi][q][r] * ivq);
        s4[r] += p;
        sx4[r] = fmaf(p, cx, sx4[r]);
      }
    }
#pragma unroll
    for (int r = 0; r < 4; ++r) {
#pragma unroll
      for (int m = 1; m < 16; m <<= 1) {
        s4[r] += __shfl_xor(s4[r], m);
        sx4[r] += __shfl_xor(sx4[r], m);
      }
    }
    if (l15 == 0) {
#pragma unroll
      for (int r = 0; r < 4; ++r) {
        int row = (wm * 9 + mi) * 16 + g * 4 + r;
        float2 o2 = make_float2(s4[r], sx4[r]);
        *(float2*)(partials + ((size_t)(b * NP + row) * 64 + jcol) * 2) = o2;
      }
    }
  }
}

// ---------------- K4: finalize ----------------
__global__ void finalize_kernel(const float* __restrict__ partials, float* __restrict__ out) {
  int b = blockIdx.x;
  int t = threadIdx.x;
  float sxt = 0.f, syt = 0.f;
  for (int i = t; i < NP; i += 256) {
    const float* p = partials + ((size_t)(b * NP + i) * 64) * 2;
    float s = 0.f, sx = 0.f, sy = 0.f;
#pragma unroll
    for (int jc2 = 0; jc2 < 64; ++jc2) {
      float ss = p[jc2 * 2];
      s += ss;
      sx += p[jc2 * 2 + 1];
      sy = fmaf(ss, (float)jc2 + 0.5f, sy);
    }
    sxt += sx / s;
    syt += sy / s;
  }
  __shared__ float rs[256], rs2[256];
  rs[t] = sxt; rs2[t] = syt;
  __syncthreads();
  for (int o = 128; o > 0; o >>= 1) {
    if (t < o) { rs[t] += rs[t + o]; rs2[t] += rs2[t + o]; }
    __syncthreads();
  }
  if (t == 0) {
    float cx = rs[0] / (float)NP, cy = rs2[0] / (float)NP;
    float l = fmaxf(cx - 12.f, 0.f);
    float tp = fmaxf(cy - 12.f, 0.f);
    out[b * 4 + 0] = l;
    out[b * 4 + 1] = tp;
    out[b * 4 + 2] = fminf(l + 24.f, 64.f);
    out[b * 4 + 3] = fminf(tp + 24.f, 64.f);
  }
}

extern "C" void kernel_launch(void* const* d_in, const int* in_sizes, int n_in,
                              void* d_out, int out_size, void* d_ws, size_t ws_size,
                              hipStream_t stream) {
  const float* patch_x = (const float*)d_in[0];
  const float* x = (const float*)d_in[1];
  float* out = (float*)d_out;
  char* ws = (char*)d_ws;

  float* inv_src = (float*)(ws + 0);                  //    73,728 B
  uint8_t* A2 = (uint8_t*)(ws + 73728);               //  9,437,184 B (fp8)
  float* partials = (float*)(ws + 9510912);           //  9,437,184 B

  norms_kernel<<<dim3((NB * NP + 255) / 256), 256, 0, stream>>>(patch_x, inv_src, NP, NB * NP);
  transpose_kernel<<<dim3(NP / 64, NC / 64, NB), 256, 0, stream>>>(patch_x, inv_src, A2, NP);
  affinity_kernel<<<dim3(1024), 512, 0, stream>>>(A2, x, partials);
  finalize_kernel<<<NB, 256, 0, stream>>>(partials, out);
}